// Round 6
// baseline (350.876 us; speedup 1.0000x reference)
//
#include <hip/hip_runtime.h>
#include <hip/hip_bf16.h>

// REGATConv on MI355X — round 6.
//   ws: fcb bf16[256*256] | ftb bf16[N*256] | el[N*4] | er[N*4] | offs[N+1] | cursor[N]
//       | rec int[E]  (packed (etype<<16)|src)
//   K1 memset cursor
//   K2 gemm+hist: MFMA bf16 GEMM (64x256 tile, wave=head) with fused fc_w->bf16 staging,
//      fused el/er epilogue, PLUS dst histogram hidden under the MFMA loop
//   K3 single-block scan -> offs, cursor=start
//   K4 scatter3: group edges by dst, 4B packed record (no gathers, no exp)
//   K5 agg4: one wave per dst node, single pass: recompute logit per lane-head,
//      o += ex*ft[src], s += ex; scale by 1/s.

#define NF 256
#define HD 256
#define NH 4

typedef __attribute__((ext_vector_type(8))) short short8;
typedef __attribute__((ext_vector_type(4))) float f32x4;

static __device__ __forceinline__ unsigned short f2bf(float f) {
  unsigned int u = __float_as_uint(f);
  u += 0x7FFFu + ((u >> 16) & 1u);   // RNE
  return (unsigned short)(u >> 16);
}
static __device__ __forceinline__ float bf2f(unsigned short s) {
  return __uint_as_float(((unsigned int)s) << 16);
}
static __device__ __forceinline__ unsigned pkbf(float a, float b) {
  __hip_bfloat162 h = __float22bfloat162_rn(make_float2(a, b));
  return *(unsigned*)&h;
}

// single-block scan, 1024 thr x 8 elem -> chunk 8192
__global__ __launch_bounds__(1024) void scan_k(int* __restrict__ cursor,
                                               int* __restrict__ offs, int n) {
  __shared__ int wtot[16];
  __shared__ int wexcl[16];
  __shared__ int ctot;
  int tid = threadIdx.x, lane = tid & 63, wid = tid >> 6;
  int carry = 0;
  int nchunk = (n + 8191) >> 13;
  for (int c = 0; c < nchunk; ++c) {
    int base = (c << 13) + tid * 8;
    int v[8];
    if (base + 8 <= n) {
      int4 a = *(const int4*)(cursor + base);
      int4 b = *(const int4*)(cursor + base + 4);
      v[0] = a.x; v[1] = a.y; v[2] = a.z; v[3] = a.w;
      v[4] = b.x; v[5] = b.y; v[6] = b.z; v[7] = b.w;
    } else {
#pragma unroll
      for (int j = 0; j < 8; ++j) v[j] = (base + j < n) ? cursor[base + j] : 0;
    }
    int p[8]; int run = 0;
#pragma unroll
    for (int j = 0; j < 8; ++j) { run += v[j]; p[j] = run; }
    int incl = run;
#pragma unroll
    for (int off = 1; off < 64; off <<= 1) {
      int t = __shfl_up(incl, off);
      if (lane >= off) incl += t;
    }
    if (lane == 63) wtot[wid] = incl;
    __syncthreads();
    if (wid == 0 && lane < 16) {
      int wv = wtot[lane]; int wi = wv;
#pragma unroll
      for (int off = 1; off < 16; off <<= 1) {
        int t = __shfl_up(wi, off);
        if (lane >= off) wi += t;
      }
      wexcl[lane] = wi - wv;
      if (lane == 15) ctot = wi;
    }
    __syncthreads();
    int ebase = carry + wexcl[wid] + (incl - run);
#pragma unroll
    for (int j = 0; j < 8; ++j) {
      int i = base + j;
      if (i < n) { int ex = ebase + p[j] - v[j]; offs[i] = ex; cursor[i] = ex; }
    }
    carry += ctot;
    __syncthreads();
  }
  if (tid == 0) offs[n] = carry;
}

// MFMA GEMM + fused dst histogram. C[m][o] = sum_k feat[m][k]*fc_w[o][k].
// Block: 64 rows x 256 cols, 4 waves; wave w owns head w. BK=64.
// Histogram: block b owns edges [b*1024, b*1024+1024), atomics issued up front
// so they drain under the MFMA K-loop.
__global__ __launch_bounds__(256) void gemm_hist_k(
    const float* __restrict__ feat, const float* __restrict__ fcw,
    const float* __restrict__ attn_l, const float* __restrict__ attn_r,
    const int* __restrict__ dst, int* __restrict__ cursor,
    unsigned short* __restrict__ ftb, float* __restrict__ el,
    float* __restrict__ er, int n, int e) {
  __shared__ short aF[4 * 2 * 64 * 8];    // [rt][s][lane][8]  8 KB
  __shared__ short bF[16 * 2 * 64 * 8];   // [cg][s][lane][8] 32 KB
  int tid = threadIdx.x;
  int lane = tid & 63, w = tid >> 6;
  int row0 = blockIdx.x * 64;

  // --- fused histogram (fire-and-forget atomics; overlap with MFMA below) ---
  {
    int eb = blockIdx.x * 1024 + tid;
#pragma unroll
    for (int j = 0; j < 4; ++j) {
      int ei = eb + j * 256;
      if (ei < e) atomicAdd(&cursor[dst[ei]], 1);
    }
  }

  f32x4 acc[4][4];
#pragma unroll
  for (int i = 0; i < 4; ++i)
#pragma unroll
    for (int j = 0; j < 4; ++j) acc[i][j] = (f32x4){0.f, 0.f, 0.f, 0.f};

  int ar = tid >> 2, ak = (tid & 3) << 4;
  int arow = row0 + ar; if (arow >= n) arow = n - 1;
  const float* ap = feat + (size_t)arow * NF + ak;
  int am = ar & 15, art = ar >> 4;
  int s0 = ak >> 5, q0 = (ak >> 3) & 3;
  int s1 = (ak + 8) >> 5, q1 = ((ak + 8) >> 3) & 3;
  short* aw0 = &aF[(((art * 2 + s0) * 64) + q0 * 16 + am) * 8];
  short* aw1 = &aF[(((art * 2 + s1) * 64) + q1 * 16 + am) * 8];

  // B staging: thread owns output col o=tid; convert fp32 fc_w -> bf16 in-register
  const float* bp = fcw + (size_t)tid * NF;
  int bn = tid & 15, bcg = tid >> 4;

  for (int k0 = 0; k0 < NF; k0 += 64) {
    float4 f0 = *(const float4*)(ap + k0);
    float4 f1 = *(const float4*)(ap + k0 + 4);
    float4 f2 = *(const float4*)(ap + k0 + 8);
    float4 f3 = *(const float4*)(ap + k0 + 12);
    uint4 oa = make_uint4(pkbf(f0.x, f0.y), pkbf(f0.z, f0.w),
                          pkbf(f1.x, f1.y), pkbf(f1.z, f1.w));
    uint4 ob = make_uint4(pkbf(f2.x, f2.y), pkbf(f2.z, f2.w),
                          pkbf(f3.x, f3.y), pkbf(f3.z, f3.w));
    *(uint4*)aw0 = oa;
    *(uint4*)aw1 = ob;
#pragma unroll
    for (int o8 = 0; o8 < 8; ++o8) {
      float4 b0 = *(const float4*)(bp + k0 + o8 * 8);
      float4 b1 = *(const float4*)(bp + k0 + o8 * 8 + 4);
      uint4 bv = make_uint4(pkbf(b0.x, b0.y), pkbf(b0.z, b0.w),
                            pkbf(b1.x, b1.y), pkbf(b1.z, b1.w));
      int bs = o8 >> 2, bq = o8 & 3;
      *(uint4*)&bF[(((bcg * 2 + bs) * 64) + bq * 16 + bn) * 8] = bv;
    }
    __syncthreads();
#pragma unroll
    for (int s = 0; s < 2; ++s) {
      short8 af[4], bfr[4];
#pragma unroll
      for (int rt = 0; rt < 4; ++rt)
        af[rt] = *(const short8*)&aF[(((rt * 2 + s) * 64) + lane) * 8];
#pragma unroll
      for (int ct = 0; ct < 4; ++ct)
        bfr[ct] = *(const short8*)&bF[((((w * 4 + ct) * 2 + s) * 64) + lane) * 8];
#pragma unroll
      for (int rt = 0; rt < 4; ++rt)
#pragma unroll
        for (int ct = 0; ct < 4; ++ct)
          acc[rt][ct] = __builtin_amdgcn_mfma_f32_16x16x32_bf16(
              af[rt], bfr[ct], acc[rt][ct], 0, 0, 0);
    }
    __syncthreads();
  }

  // epilogue: wave w == head w. C/D map: col = lane&15, row = (lane>>4)*4 + r.
  int ln = lane & 15, lq = lane >> 4;
  float al4[4], ar4[4];
#pragma unroll
  for (int ct = 0; ct < 4; ++ct) {
    al4[ct] = attn_l[w * 64 + ct * 16 + ln];
    ar4[ct] = attn_r[w * 64 + ct * 16 + ln];
  }
#pragma unroll
  for (int rt = 0; rt < 4; ++rt) {
#pragma unroll
    for (int r = 0; r < 4; ++r) {
      float pl = 0.f, pr = 0.f;
#pragma unroll
      for (int ct = 0; ct < 4; ++ct) {
        float v = acc[rt][ct][r];
        pl += v * al4[ct]; pr += v * ar4[ct];
      }
#pragma unroll
      for (int off = 1; off <= 8; off <<= 1) {
        pl += __shfl_xor(pl, off);
        pr += __shfl_xor(pr, off);
      }
      int row = row0 + rt * 16 + lq * 4 + r;
      if (row < n) {
        if (ln == 0) { el[row * NH + w] = pl; er[row * NH + w] = pr; }
        unsigned short* fr = ftb + (size_t)row * HD + w * 64 + ln;
#pragma unroll
        for (int ct = 0; ct < 4; ++ct) fr[ct * 16] = f2bf(acc[rt][ct][r]);
      }
    }
  }
}

// group edges by dst: one packed 4B record (etype<<16)|src  (src < 65536)
__global__ __launch_bounds__(256) void scatter3_k(
    const int* __restrict__ src, const int* __restrict__ dst,
    const int* __restrict__ efeats, int* __restrict__ cursor,
    int* __restrict__ rec, int e) {
  int i = blockIdx.x * 256 + threadIdx.x;
  if (i >= e) return;
  int p = atomicAdd(&cursor[dst[i]], 1);
  rec[p] = ((efeats[i] - 1) << 16) | src[i];
}

// one wave per dst node; lane owns output cols lane*4..+3 (head hl=lane>>4).
// Single pass: recompute logit (el gather broadcasts one line/wave/edge),
// o += ex*ft[src], s += ex; scale by 1/s at the end.
__global__ __launch_bounds__(256) void agg4_k(
    const unsigned short* __restrict__ ftb, const float* __restrict__ el,
    const float* __restrict__ er, const int* __restrict__ rec,
    const float* __restrict__ ewt, const int* __restrict__ offs,
    float* __restrict__ out, int n) {
  __shared__ float ew_s[32];
  if (threadIdx.x < 32) {
    float v = ewt[threadIdx.x] * 100.0f;
    ew_s[threadIdx.x] = (v >= 0.f) ? v : 0.01f * v;
  }
  __syncthreads();
  int node = blockIdx.x * 4 + (threadIdx.x >> 6);
  int lane = threadIdx.x & 63;
  if (node >= n) return;
  int start = offs[node];
  int deg = offs[node + 1] - start;
  float o0 = 0.f, o1 = 0.f, o2 = 0.f, o3 = 0.f;
  float s = 0.f;
  int hl = lane >> 4;
  const unsigned short* fb = ftb + (size_t)lane * 4;
  const int* rp = rec + start;
  if (deg > 0) {
    float erh = er[(size_t)node * 4 + hl];
    const float* ewh = ew_s + hl;
    int i = 0;
    for (; i + 8 <= deg; i += 8) {
      int r0 = rp[i],     r1 = rp[i + 1], r2 = rp[i + 2], r3 = rp[i + 3];
      int r4 = rp[i + 4], r5 = rp[i + 5], r6 = rp[i + 6], r7 = rp[i + 7];
      int s0 = r0 & 0xffff, s1 = r1 & 0xffff, s2 = r2 & 0xffff, s3 = r3 & 0xffff;
      int s4 = r4 & 0xffff, s5 = r5 & 0xffff, s6 = r6 & 0xffff, s7 = r7 & 0xffff;
      ushort4 f0 = *(const ushort4*)(fb + (size_t)s0 * HD);
      ushort4 f1 = *(const ushort4*)(fb + (size_t)s1 * HD);
      ushort4 f2 = *(const ushort4*)(fb + (size_t)s2 * HD);
      ushort4 f3 = *(const ushort4*)(fb + (size_t)s3 * HD);
      ushort4 f4 = *(const ushort4*)(fb + (size_t)s4 * HD);
      ushort4 f5 = *(const ushort4*)(fb + (size_t)s5 * HD);
      ushort4 f6 = *(const ushort4*)(fb + (size_t)s6 * HD);
      ushort4 f7 = *(const ushort4*)(fb + (size_t)s7 * HD);
      float x0 = (el[(size_t)s0 * 4 + hl] + erh) * ewh[(r0 >> 16) * 4];
      float x1 = (el[(size_t)s1 * 4 + hl] + erh) * ewh[(r1 >> 16) * 4];
      float x2 = (el[(size_t)s2 * 4 + hl] + erh) * ewh[(r2 >> 16) * 4];
      float x3 = (el[(size_t)s3 * 4 + hl] + erh) * ewh[(r3 >> 16) * 4];
      float x4 = (el[(size_t)s4 * 4 + hl] + erh) * ewh[(r4 >> 16) * 4];
      float x5 = (el[(size_t)s5 * 4 + hl] + erh) * ewh[(r5 >> 16) * 4];
      float x6 = (el[(size_t)s6 * 4 + hl] + erh) * ewh[(r6 >> 16) * 4];
      float x7 = (el[(size_t)s7 * 4 + hl] + erh) * ewh[(r7 >> 16) * 4];
      x0 = (x0 >= 0.f) ? x0 : 0.2f * x0;  x1 = (x1 >= 0.f) ? x1 : 0.2f * x1;
      x2 = (x2 >= 0.f) ? x2 : 0.2f * x2;  x3 = (x3 >= 0.f) ? x3 : 0.2f * x3;
      x4 = (x4 >= 0.f) ? x4 : 0.2f * x4;  x5 = (x5 >= 0.f) ? x5 : 0.2f * x5;
      x6 = (x6 >= 0.f) ? x6 : 0.2f * x6;  x7 = (x7 >= 0.f) ? x7 : 0.2f * x7;
      float e0 = __expf(x0), e1 = __expf(x1), e2 = __expf(x2), e3 = __expf(x3);
      float e4 = __expf(x4), e5 = __expf(x5), e6 = __expf(x6), e7 = __expf(x7);
      s += ((e0 + e1) + (e2 + e3)) + ((e4 + e5) + (e6 + e7));
      o0 = fmaf(e0, bf2f(f0.x), o0); o1 = fmaf(e0, bf2f(f0.y), o1);
      o2 = fmaf(e0, bf2f(f0.z), o2); o3 = fmaf(e0, bf2f(f0.w), o3);
      o0 = fmaf(e1, bf2f(f1.x), o0); o1 = fmaf(e1, bf2f(f1.y), o1);
      o2 = fmaf(e1, bf2f(f1.z), o2); o3 = fmaf(e1, bf2f(f1.w), o3);
      o0 = fmaf(e2, bf2f(f2.x), o0); o1 = fmaf(e2, bf2f(f2.y), o1);
      o2 = fmaf(e2, bf2f(f2.z), o2); o3 = fmaf(e2, bf2f(f2.w), o3);
      o0 = fmaf(e3, bf2f(f3.x), o0); o1 = fmaf(e3, bf2f(f3.y), o1);
      o2 = fmaf(e3, bf2f(f3.z), o2); o3 = fmaf(e3, bf2f(f3.w), o3);
      o0 = fmaf(e4, bf2f(f4.x), o0); o1 = fmaf(e4, bf2f(f4.y), o1);
      o2 = fmaf(e4, bf2f(f4.z), o2); o3 = fmaf(e4, bf2f(f4.w), o3);
      o0 = fmaf(e5, bf2f(f5.x), o0); o1 = fmaf(e5, bf2f(f5.y), o1);
      o2 = fmaf(e5, bf2f(f5.z), o2); o3 = fmaf(e5, bf2f(f5.w), o3);
      o0 = fmaf(e6, bf2f(f6.x), o0); o1 = fmaf(e6, bf2f(f6.y), o1);
      o2 = fmaf(e6, bf2f(f6.z), o2); o3 = fmaf(e6, bf2f(f6.w), o3);
      o0 = fmaf(e7, bf2f(f7.x), o0); o1 = fmaf(e7, bf2f(f7.y), o1);
      o2 = fmaf(e7, bf2f(f7.z), o2); o3 = fmaf(e7, bf2f(f7.w), o3);
    }
    for (; i < deg; ++i) {
      int r0 = rp[i];
      int s0 = r0 & 0xffff;
      ushort4 f0 = *(const ushort4*)(fb + (size_t)s0 * HD);
      float x0 = (el[(size_t)s0 * 4 + hl] + erh) * ewh[(r0 >> 16) * 4];
      x0 = (x0 >= 0.f) ? x0 : 0.2f * x0;
      float e0 = __expf(x0);
      s += e0;
      o0 = fmaf(e0, bf2f(f0.x), o0); o1 = fmaf(e0, bf2f(f0.y), o1);
      o2 = fmaf(e0, bf2f(f0.z), o2); o3 = fmaf(e0, bf2f(f0.w), o3);
    }
    float rs = 1.0f / s;
    o0 *= rs; o1 *= rs; o2 *= rs; o3 *= rs;
  }
  *(float4*)(out + (size_t)node * HD + lane * 4) = make_float4(o0, o1, o2, o3);
}

extern "C" void kernel_launch(void* const* d_in, const int* in_sizes, int n_in,
                              void* d_out, int out_size, void* d_ws, size_t ws_size,
                              hipStream_t stream) {
  const float* feat   = (const float*)d_in[0];
  const int*   src    = (const int*)d_in[1];
  const int*   dst    = (const int*)d_in[2];
  const int*   efeats = (const int*)d_in[3];
  const float* fc_w   = (const float*)d_in[4];
  const float* attn_l = (const float*)d_in[5];
  const float* attn_r = (const float*)d_in[6];
  const float* ewt    = (const float*)d_in[7];
  float* out = (float*)d_out;

  int N = in_sizes[0] / NF;   // 50000
  int E = in_sizes[1];        // 800000

  char* ws = (char*)d_ws;
  size_t off = 0;
  unsigned short* ftb = (unsigned short*)(ws + off); off += (size_t)N * HD * 2;   // 25.6 MB
  float* el  = (float*)(ws + off);  off += (size_t)N * NH * 4;
  float* er  = (float*)(ws + off);  off += (size_t)N * NH * 4;
  int* offs  = (int*)(ws + off);    off += ((size_t)N + 16) * 4;
  int* cursor = (int*)(ws + off);   off += (size_t)N * 4;
  int* rec   = (int*)(ws + off);    off += (size_t)E * 4;                          // 3.2 MB

  int nblk = (N + 63) / 64;              // 782
  int eblk = (E + 1023) / 1024;          // 782  (gemm grid covers both)
  int gblk = nblk > eblk ? nblk : eblk;

  hipMemsetAsync(cursor, 0, (size_t)N * 4, stream);
  gemm_hist_k<<<gblk, 256, 0, stream>>>(feat, fc_w, attn_l, attn_r, dst, cursor,
                                        ftb, el, er, N, E);
  scan_k<<<1, 1024, 0, stream>>>(cursor, offs, N);
  scatter3_k<<<(E + 255) / 256, 256, 0, stream>>>(src, dst, efeats, cursor, rec, E);
  agg4_k<<<(N + 3) / 4, 256, 0, stream>>>(ftb, el, er, rec, ewt, offs, out, N);
}

// Round 7
// 304.049 us; speedup vs baseline: 1.1540x; 1.1540x over previous
//
#include <hip/hip_runtime.h>
#include <hip/hip_bf16.h>

// REGATConv on MI355X — round 7. R4 structure + rank-trick scatter (no atomics).
//   ws: fcb bf16[256*256] | ftb bf16[N*256] | el[N*4] | er[N*4] | offs[N+1] | cursor[N]
//       | rank int[E] | srcs_g int[E] | exq float4[E]
//   K1 memset cursor
//   K2 hist_cvt_rank: rank[i]=atomicAdd(cursor[dst[i]],1) + fc_w->bf16 convert
//   K3 single-block scan -> offs
//   K4 MFMA bf16 GEMM (64x256 tile, wave=head), fused el/er epilogue -> ftb, el, er
//   K5 scatter4: p = offs[dst]+rank (NO atomic); srcs_g[p]=src, exq[p]=exp(leaky(...))
//   K6 agg2: one wave per dst node: seq exq sum -> 1/s, then 8x-unrolled ftb gather

#define NF 256
#define HD 256
#define NH 4

typedef __attribute__((ext_vector_type(8))) short short8;
typedef __attribute__((ext_vector_type(4))) float f32x4;

static __device__ __forceinline__ unsigned short f2bf(float f) {
  unsigned int u = __float_as_uint(f);
  u += 0x7FFFu + ((u >> 16) & 1u);   // RNE
  return (unsigned short)(u >> 16);
}
static __device__ __forceinline__ float bf2f(unsigned short s) {
  return __uint_as_float(((unsigned int)s) << 16);
}
static __device__ __forceinline__ unsigned pkbf(float a, float b) {
  __hip_bfloat162 h = __float22bfloat162_rn(make_float2(a, b));
  return *(unsigned*)&h;
}

// fused: dst histogram (stores per-edge rank) + fc_w fp32->bf16 convert
__global__ __launch_bounds__(256) void hist_cvt_rank_k(
    const int* __restrict__ dst, int* __restrict__ cursor,
    int* __restrict__ rank, const float* __restrict__ w,
    unsigned short* __restrict__ o, int e) {
  int i = blockIdx.x * 256 + threadIdx.x;
  if (i < 16384) {
    float4 v = ((const float4*)w)[i];
    ((uint2*)o)[i] = make_uint2(pkbf(v.x, v.y), pkbf(v.z, v.w));
  }
  if (i < e) rank[i] = atomicAdd(&cursor[dst[i]], 1);
}

// single-block scan, 1024 thr x 8 elem -> chunk 8192
__global__ __launch_bounds__(1024) void scan_k(const int* __restrict__ cursor,
                                               int* __restrict__ offs, int n) {
  __shared__ int wtot[16];
  __shared__ int wexcl[16];
  __shared__ int ctot;
  int tid = threadIdx.x, lane = tid & 63, wid = tid >> 6;
  int carry = 0;
  int nchunk = (n + 8191) >> 13;
  for (int c = 0; c < nchunk; ++c) {
    int base = (c << 13) + tid * 8;
    int v[8];
    if (base + 8 <= n) {
      int4 a = *(const int4*)(cursor + base);
      int4 b = *(const int4*)(cursor + base + 4);
      v[0] = a.x; v[1] = a.y; v[2] = a.z; v[3] = a.w;
      v[4] = b.x; v[5] = b.y; v[6] = b.z; v[7] = b.w;
    } else {
#pragma unroll
      for (int j = 0; j < 8; ++j) v[j] = (base + j < n) ? cursor[base + j] : 0;
    }
    int p[8]; int run = 0;
#pragma unroll
    for (int j = 0; j < 8; ++j) { run += v[j]; p[j] = run; }
    int incl = run;
#pragma unroll
    for (int off = 1; off < 64; off <<= 1) {
      int t = __shfl_up(incl, off);
      if (lane >= off) incl += t;
    }
    if (lane == 63) wtot[wid] = incl;
    __syncthreads();
    if (wid == 0 && lane < 16) {
      int wv = wtot[lane]; int wi = wv;
#pragma unroll
      for (int off = 1; off < 16; off <<= 1) {
        int t = __shfl_up(wi, off);
        if (lane >= off) wi += t;
      }
      wexcl[lane] = wi - wv;
      if (lane == 15) ctot = wi;
    }
    __syncthreads();
    int ebase = carry + wexcl[wid] + (incl - run);
#pragma unroll
    for (int j = 0; j < 8; ++j) {
      int i = base + j;
      if (i < n) offs[i] = ebase + p[j] - v[j];
    }
    carry += ctot;
    __syncthreads();
  }
  if (tid == 0) offs[n] = carry;
}

// MFMA GEMM: C[m][o] = sum_k feat[m][k]*fc_w[o][k]. Block: 64 rows x 256 cols,
// 4 waves; wave w owns cols [w*64, w*64+64) == head w. BK=64 (2 mfma k-steps).
__global__ __launch_bounds__(256) void gemm_k(
    const float* __restrict__ feat, const unsigned short* __restrict__ fcb,
    const float* __restrict__ attn_l, const float* __restrict__ attn_r,
    unsigned short* __restrict__ ftb, float* __restrict__ el,
    float* __restrict__ er, int n) {
  __shared__ short aF[4 * 2 * 64 * 8];    // [rt][s][lane][8]  8 KB
  __shared__ short bF[16 * 2 * 64 * 8];   // [cg][s][lane][8] 32 KB
  int tid = threadIdx.x;
  int lane = tid & 63, w = tid >> 6;
  int row0 = blockIdx.x * 64;

  f32x4 acc[4][4];
#pragma unroll
  for (int i = 0; i < 4; ++i)
#pragma unroll
    for (int j = 0; j < 4; ++j) acc[i][j] = (f32x4){0.f, 0.f, 0.f, 0.f};

  int ar = tid >> 2, ak = (tid & 3) << 4;
  int arow = row0 + ar; if (arow >= n) arow = n - 1;
  const float* ap = feat + (size_t)arow * NF + ak;
  int am = ar & 15, art = ar >> 4;
  int s0 = ak >> 5, q0 = (ak >> 3) & 3;
  int s1 = (ak + 8) >> 5, q1 = ((ak + 8) >> 3) & 3;
  short* aw0 = &aF[(((art * 2 + s0) * 64) + q0 * 16 + am) * 8];
  short* aw1 = &aF[(((art * 2 + s1) * 64) + q1 * 16 + am) * 8];

  const unsigned short* bp = fcb + (size_t)tid * NF;
  int bn = tid & 15, bcg = tid >> 4;

  for (int k0 = 0; k0 < NF; k0 += 64) {
    float4 f0 = *(const float4*)(ap + k0);
    float4 f1 = *(const float4*)(ap + k0 + 4);
    float4 f2 = *(const float4*)(ap + k0 + 8);
    float4 f3 = *(const float4*)(ap + k0 + 12);
    uint4 oa = make_uint4(pkbf(f0.x, f0.y), pkbf(f0.z, f0.w),
                          pkbf(f1.x, f1.y), pkbf(f1.z, f1.w));
    uint4 ob = make_uint4(pkbf(f2.x, f2.y), pkbf(f2.z, f2.w),
                          pkbf(f3.x, f3.y), pkbf(f3.z, f3.w));
    *(uint4*)aw0 = oa;
    *(uint4*)aw1 = ob;
#pragma unroll
    for (int o8 = 0; o8 < 8; ++o8) {
      short8 bv = *(const short8*)(bp + k0 + o8 * 8);
      int bs = o8 >> 2, bq = o8 & 3;
      *(short8*)&bF[(((bcg * 2 + bs) * 64) + bq * 16 + bn) * 8] = bv;
    }
    __syncthreads();
#pragma unroll
    for (int s = 0; s < 2; ++s) {
      short8 af[4], bfr[4];
#pragma unroll
      for (int rt = 0; rt < 4; ++rt)
        af[rt] = *(const short8*)&aF[(((rt * 2 + s) * 64) + lane) * 8];
#pragma unroll
      for (int ct = 0; ct < 4; ++ct)
        bfr[ct] = *(const short8*)&bF[((((w * 4 + ct) * 2 + s) * 64) + lane) * 8];
#pragma unroll
      for (int rt = 0; rt < 4; ++rt)
#pragma unroll
        for (int ct = 0; ct < 4; ++ct)
          acc[rt][ct] = __builtin_amdgcn_mfma_f32_16x16x32_bf16(
              af[rt], bfr[ct], acc[rt][ct], 0, 0, 0);
    }
    __syncthreads();
  }

  // epilogue: wave w == head w. C/D map: col = lane&15, row = (lane>>4)*4 + r.
  int ln = lane & 15, lq = lane >> 4;
  float al4[4], ar4[4];
#pragma unroll
  for (int ct = 0; ct < 4; ++ct) {
    al4[ct] = attn_l[w * 64 + ct * 16 + ln];
    ar4[ct] = attn_r[w * 64 + ct * 16 + ln];
  }
#pragma unroll
  for (int rt = 0; rt < 4; ++rt) {
#pragma unroll
    for (int r = 0; r < 4; ++r) {
      float pl = 0.f, pr = 0.f;
#pragma unroll
      for (int ct = 0; ct < 4; ++ct) {
        float v = acc[rt][ct][r];
        pl += v * al4[ct]; pr += v * ar4[ct];
      }
#pragma unroll
      for (int off = 1; off <= 8; off <<= 1) {
        pl += __shfl_xor(pl, off);
        pr += __shfl_xor(pr, off);
      }
      int row = row0 + rt * 16 + lq * 4 + r;
      if (row < n) {
        if (ln == 0) { el[row * NH + w] = pl; er[row * NH + w] = pr; }
        unsigned short* fr = ftb + (size_t)row * HD + w * 64 + ln;
#pragma unroll
        for (int ct = 0; ct < 4; ++ct) fr[ct * 16] = f2bf(acc[rt][ct][r]);
      }
    }
  }
}

// group edges by dst via p = offs[dst] + rank  (NO atomics)
__global__ __launch_bounds__(256) void scatter4_k(
    const int* __restrict__ src, const int* __restrict__ dst,
    const int* __restrict__ efeats, const int* __restrict__ rank,
    const int* __restrict__ offs, const float* __restrict__ el,
    const float* __restrict__ er, const float* __restrict__ ewt,
    int* __restrict__ srcs_g, float4* __restrict__ exq, int e) {
  __shared__ float ew_s[32];
  if (threadIdx.x < 32) {
    float v = ewt[threadIdx.x] * 100.0f;
    ew_s[threadIdx.x] = (v >= 0.f) ? v : 0.01f * v;
  }
  __syncthreads();
  int i = blockIdx.x * 256 + threadIdx.x;
  if (i >= e) return;
  int d = dst[i], s = src[i], t = efeats[i] - 1;
  int p = offs[d] + rank[i];
  float4 elv = *(const float4*)(el + (size_t)s * 4);
  float4 erv = *(const float4*)(er + (size_t)d * 4);
  const float* ew = &ew_s[t * 4];
  float x0 = (elv.x + erv.x) * ew[0]; x0 = (x0 >= 0.f) ? x0 : 0.2f * x0;
  float x1 = (elv.y + erv.y) * ew[1]; x1 = (x1 >= 0.f) ? x1 : 0.2f * x1;
  float x2 = (elv.z + erv.z) * ew[2]; x2 = (x2 >= 0.f) ? x2 : 0.2f * x2;
  float x3 = (elv.w + erv.w) * ew[3]; x3 = (x3 >= 0.f) ? x3 : 0.2f * x3;
  exq[p] = make_float4(__expf(x0), __expf(x1), __expf(x2), __expf(x3));
  srcs_g[p] = s;
}

// one wave per dst node; lane owns output cols lane*4..lane*4+3 (head hl=lane>>4).
__global__ __launch_bounds__(256) void agg2_k(
    const unsigned short* __restrict__ ftb, const int* __restrict__ srcs_g,
    const float4* __restrict__ exq, const int* __restrict__ offs,
    float* __restrict__ out, int n) {
  int node = blockIdx.x * 4 + (threadIdx.x >> 6);
  int lane = threadIdx.x & 63;
  if (node >= n) return;
  int start = offs[node];
  int deg = offs[node + 1] - start;
  float o0 = 0.f, o1 = 0.f, o2 = 0.f, o3 = 0.f;
  if (deg > 0) {
    // pass A: sequential sum of exq over the group (coalesced float4 loads)
    float s0 = 0.f, s1 = 0.f, s2 = 0.f, s3 = 0.f;
    for (int i = lane; i < deg; i += 64) {
      float4 q = exq[(size_t)start + i];
      s0 += q.x; s1 += q.y; s2 += q.z; s3 += q.w;
    }
#pragma unroll
    for (int off = 1; off < 64; off <<= 1) {
      s0 += __shfl_xor(s0, off);
      s1 += __shfl_xor(s1, off);
      s2 += __shfl_xor(s2, off);
      s3 += __shfl_xor(s3, off);
    }
    int hl = lane >> 4;
    float sh = (hl == 0) ? s0 : (hl == 1) ? s1 : (hl == 2) ? s2 : s3;
    float rs = 1.0f / sh;
    // pass C: 8x-unrolled gather (8 outstanding 8B loads/lane)
    const float* exs = (const float*)exq;
    const unsigned short* fb = ftb + (size_t)lane * 4;
    const int* sg = srcs_g + start;
    long b4 = (long)start * 4 + hl;
    int i = 0;
    for (; i + 8 <= deg; i += 8) {
      int sA = sg[i],     sB = sg[i + 1], sC = sg[i + 2], sD = sg[i + 3];
      int sE = sg[i + 4], sF = sg[i + 5], sG = sg[i + 6], sH = sg[i + 7];
      ushort4 fA = *(const ushort4*)(fb + (size_t)sA * HD);
      ushort4 fB = *(const ushort4*)(fb + (size_t)sB * HD);
      ushort4 fC = *(const ushort4*)(fb + (size_t)sC * HD);
      ushort4 fD = *(const ushort4*)(fb + (size_t)sD * HD);
      ushort4 fE = *(const ushort4*)(fb + (size_t)sE * HD);
      ushort4 fF = *(const ushort4*)(fb + (size_t)sF * HD);
      ushort4 fG = *(const ushort4*)(fb + (size_t)sG * HD);
      ushort4 fH = *(const ushort4*)(fb + (size_t)sH * HD);
      float wA = exs[b4 + (long)i * 4]       * rs;
      float wB = exs[b4 + (long)(i + 1) * 4] * rs;
      float wC = exs[b4 + (long)(i + 2) * 4] * rs;
      float wD = exs[b4 + (long)(i + 3) * 4] * rs;
      float wE = exs[b4 + (long)(i + 4) * 4] * rs;
      float wF = exs[b4 + (long)(i + 5) * 4] * rs;
      float wG = exs[b4 + (long)(i + 6) * 4] * rs;
      float wH = exs[b4 + (long)(i + 7) * 4] * rs;
      o0 = fmaf(wA, bf2f(fA.x), o0); o1 = fmaf(wA, bf2f(fA.y), o1);
      o2 = fmaf(wA, bf2f(fA.z), o2); o3 = fmaf(wA, bf2f(fA.w), o3);
      o0 = fmaf(wB, bf2f(fB.x), o0); o1 = fmaf(wB, bf2f(fB.y), o1);
      o2 = fmaf(wB, bf2f(fB.z), o2); o3 = fmaf(wB, bf2f(fB.w), o3);
      o0 = fmaf(wC, bf2f(fC.x), o0); o1 = fmaf(wC, bf2f(fC.y), o1);
      o2 = fmaf(wC, bf2f(fC.z), o2); o3 = fmaf(wC, bf2f(fC.w), o3);
      o0 = fmaf(wD, bf2f(fD.x), o0); o1 = fmaf(wD, bf2f(fD.y), o1);
      o2 = fmaf(wD, bf2f(fD.z), o2); o3 = fmaf(wD, bf2f(fD.w), o3);
      o0 = fmaf(wE, bf2f(fE.x), o0); o1 = fmaf(wE, bf2f(fE.y), o1);
      o2 = fmaf(wE, bf2f(fE.z), o2); o3 = fmaf(wE, bf2f(fE.w), o3);
      o0 = fmaf(wF, bf2f(fF.x), o0); o1 = fmaf(wF, bf2f(fF.y), o1);
      o2 = fmaf(wF, bf2f(fF.z), o2); o3 = fmaf(wF, bf2f(fF.w), o3);
      o0 = fmaf(wG, bf2f(fG.x), o0); o1 = fmaf(wG, bf2f(fG.y), o1);
      o2 = fmaf(wG, bf2f(fG.z), o2); o3 = fmaf(wG, bf2f(fG.w), o3);
      o0 = fmaf(wH, bf2f(fH.x), o0); o1 = fmaf(wH, bf2f(fH.y), o1);
      o2 = fmaf(wH, bf2f(fH.z), o2); o3 = fmaf(wH, bf2f(fH.w), o3);
    }
    for (; i < deg; ++i) {
      int sA = sg[i];
      float wA = exs[b4 + (long)i * 4] * rs;
      ushort4 fA = *(const ushort4*)(fb + (size_t)sA * HD);
      o0 = fmaf(wA, bf2f(fA.x), o0); o1 = fmaf(wA, bf2f(fA.y), o1);
      o2 = fmaf(wA, bf2f(fA.z), o2); o3 = fmaf(wA, bf2f(fA.w), o3);
    }
  }
  *(float4*)(out + (size_t)node * HD + lane * 4) = make_float4(o0, o1, o2, o3);
}

extern "C" void kernel_launch(void* const* d_in, const int* in_sizes, int n_in,
                              void* d_out, int out_size, void* d_ws, size_t ws_size,
                              hipStream_t stream) {
  const float* feat   = (const float*)d_in[0];
  const int*   src    = (const int*)d_in[1];
  const int*   dst    = (const int*)d_in[2];
  const int*   efeats = (const int*)d_in[3];
  const float* fc_w   = (const float*)d_in[4];
  const float* attn_l = (const float*)d_in[5];
  const float* attn_r = (const float*)d_in[6];
  const float* ewt    = (const float*)d_in[7];
  float* out = (float*)d_out;

  int N = in_sizes[0] / NF;   // 50000
  int E = in_sizes[1];        // 800000

  char* ws = (char*)d_ws;
  size_t off = 0;
  unsigned short* fcb = (unsigned short*)(ws + off); off += (size_t)NF * HD * 2;  // 128 KB
  unsigned short* ftb = (unsigned short*)(ws + off); off += (size_t)N * HD * 2;   // 25.6 MB
  float* el  = (float*)(ws + off);  off += (size_t)N * NH * 4;
  float* er  = (float*)(ws + off);  off += (size_t)N * NH * 4;
  int* offs  = (int*)(ws + off);    off += ((size_t)N + 16) * 4;
  int* cursor = (int*)(ws + off);   off += (size_t)N * 4;
  int* rank  = (int*)(ws + off);    off += (size_t)E * 4;                          // 3.2 MB
  int* srcs_g = (int*)(ws + off);   off += (size_t)E * 4;                          // 3.2 MB
  float4* exq = (float4*)(ws + off); off += (size_t)E * 16;                        // 12.8 MB

  hipMemsetAsync(cursor, 0, (size_t)N * 4, stream);
  hist_cvt_rank_k<<<(E + 255) / 256, 256, 0, stream>>>(dst, cursor, rank, fc_w, fcb, E);
  scan_k<<<1, 1024, 0, stream>>>(cursor, offs, N);
  gemm_k<<<(N + 63) / 64, 256, 0, stream>>>(feat, fcb, attn_l, attn_r, ftb, el, er, N);
  scatter4_k<<<(E + 255) / 256, 256, 0, stream>>>(src, dst, efeats, rank, offs,
                                                  el, er, ewt, srcs_g, exq, E);
  agg2_k<<<(N + 3) / 4, 256, 0, stream>>>(ftb, srcs_g, exq, offs, out, N);
}